// Round 1
// baseline (237.730 us; speedup 1.0000x reference)
//
#include <hip/hip_runtime.h>

// GCN conv: out = mean-aggregate(x over CSR) @ W + bias
// Strategy: aggregate x into d_out (fp32), then in-place row GEMM d_out = d_out @ W + bias.

#define NN 100000
#define D 128
#define ROWS_PER_BLK 8

// One wave (64 lanes) per node; lane l owns channels 2l, 2l+1 (float2).
// 4 nodes per 256-thread block.
__global__ __launch_bounds__(256) void agg_x(const float* __restrict__ x,
                                             const int* __restrict__ ptr,
                                             const int* __restrict__ idx,
                                             float* __restrict__ out) {
  int node = blockIdx.x * 4 + (threadIdx.x >> 6);
  int lane = threadIdx.x & 63;
  if (node >= NN) return;
  int p0 = ptr[node];
  int p1 = ptr[node + 1];
  float sx = 0.f, sy = 0.f;
  for (int e = p0; e < p1; ++e) {
    int nid = idx[e];
    const float2 v = ((const float2*)(x + (size_t)nid * D))[lane];
    sx += v.x;
    sy += v.y;
  }
  int deg = p1 - p0;
  float inv = (deg > 0) ? (1.0f / (float)deg) : 0.0f;
  float2 r;
  r.x = sx * inv;
  r.y = sy * inv;
  ((float2*)(out + (size_t)node * D))[lane] = r;
}

// In-place row GEMM: io[r,:] = io[r,:] @ W + bias.
// W staged in LDS (64 KB) once per block; grid-stride over row groups of 8.
// Thread t: row (t>>5) of the group, output cols 4*(t&31)..4*(t&31)+3.
__global__ __launch_bounds__(256) void rowgemm_inplace(float* __restrict__ io,
                                                       const float* __restrict__ W,
                                                       const float* __restrict__ bias) {
  __shared__ float4 Wl[D * 32];            // 64 KB: W[k][c], float4 over c
  __shared__ float xr[ROWS_PER_BLK][D];    // 4 KB: staged input rows
  int tid = threadIdx.x;
  for (int i = tid; i < D * 32; i += 256)
    Wl[i] = ((const float4*)W)[i];
  int r = tid >> 5;   // 0..7
  int c4 = tid & 31;  // 0..31
  float4 b4 = ((const float4*)bias)[c4];
  __syncthreads();

  const int ngroups = NN / ROWS_PER_BLK;  // 12500, exact
  for (int g = blockIdx.x; g < ngroups; g += gridDim.x) {
    size_t base = (size_t)g * ROWS_PER_BLK;
    // stage 8 rows (1024 floats = 256 float4): float4 i -> row i/32, cols (i%32)*4
    ((float4*)xr)[tid] = ((const float4*)(io + base * D))[tid];
    __syncthreads();
    float4 acc = b4;
#pragma unroll 8
    for (int k = 0; k < D; ++k) {
      float xv = xr[r][k];
      float4 w = Wl[k * 32 + c4];
      acc.x = fmaf(xv, w.x, acc.x);
      acc.y = fmaf(xv, w.y, acc.y);
      acc.z = fmaf(xv, w.z, acc.z);
      acc.w = fmaf(xv, w.w, acc.w);
    }
    ((float4*)(io + (base + (size_t)r) * D))[c4] = acc;
    __syncthreads();  // protect xr before next group's stage
  }
}

extern "C" void kernel_launch(void* const* d_in, const int* in_sizes, int n_in,
                              void* d_out, int out_size, void* d_ws, size_t ws_size,
                              hipStream_t stream) {
  const float* x = (const float*)d_in[0];
  const float* W = (const float*)d_in[1];
  const float* bias = (const float*)d_in[2];
  const int* ptr = (const int*)d_in[3];
  const int* idx = (const int*)d_in[4];
  float* out = (float*)d_out;

  // Step 1: out = mean-aggregated x  (4 nodes per block)
  agg_x<<<NN / 4, 256, 0, stream>>>(x, ptr, idx, out);
  // Step 2: out = out @ W + bias, in place
  rowgemm_inplace<<<1280, 256, 0, stream>>>(out, W, bias);
}

// Round 2
// 159.032 us; speedup vs baseline: 1.4949x; 1.4949x over previous
//
#include <hip/hip_runtime.h>
#include <hip/hip_bf16.h>

// GCN conv: out = mean-aggregate(h over CSR) + bias, h = x @ W.
// R2: h stored as bf16 in ws (halves gather bytes); GEMM via bf16 MFMA.

#define NN 100000
#define D 128

using short8 = __attribute__((ext_vector_type(8))) short;
using f32x4 = __attribute__((ext_vector_type(4))) float;

// ---------- Kernel 1: h[n][c] = sum_k x[n][k] * W[k][c], h in bf16 ----------
// 256 thr = 4 waves; each wave: 16 rows x 128 cols via mfma_f32_16x16x32_bf16.
__global__ __launch_bounds__(256) void gemm_xw_bf16(const float* __restrict__ x,
                                                    const float* __restrict__ W,
                                                    __hip_bfloat16* __restrict__ h) {
  __shared__ __hip_bfloat16 Wl[D][D + 8];  // transposed: Wl[col][k], +8 pad (2-way free aliasing)
  int tid = threadIdx.x;
  for (int i = tid; i < D * D; i += 256) {
    int k = i >> 7, c = i & 127;
    Wl[c][k] = __float2bfloat16(W[i]);
  }
  __syncthreads();

  int wid = tid >> 6, lane = tid & 63;
  int r0 = (blockIdx.x * 4 + wid) * 16;
  if (r0 >= NN) return;           // 100000 % 16 == 0, so waves are all-or-nothing
  int c16 = lane & 15;
  int kc = lane >> 4;             // k-chunk 0..3

  // A fragments: lane holds A[r0 + (lane&15)][kk*32 + kc*8 + j], j=0..7
  short8 a[4];
  const float* xrow = x + (size_t)(r0 + c16) * D + kc * 8;
#pragma unroll
  for (int kk = 0; kk < 4; ++kk) {
    const float* p = xrow + kk * 32;
#pragma unroll
    for (int j = 0; j < 8; ++j) {
      __hip_bfloat16 bv = __float2bfloat16(p[j]);
      a[kk][j] = *reinterpret_cast<short*>(&bv);
    }
  }

  f32x4 acc[8];
#pragma unroll
  for (int ct = 0; ct < 8; ++ct) acc[ct] = (f32x4)(0.0f);

#pragma unroll
  for (int kk = 0; kk < 4; ++kk) {
#pragma unroll
    for (int ct = 0; ct < 8; ++ct) {
      // B fragment: B[kk*32 + kc*8 + j][ct*16 + c16] = Wl[ct*16+c16][kk*32+kc*8+j]
      short8 b = *reinterpret_cast<const short8*>(&Wl[ct * 16 + c16][kk * 32 + kc * 8]);
      acc[ct] = __builtin_amdgcn_mfma_f32_16x16x32_bf16(a[kk], b, acc[ct], 0, 0, 0);
    }
  }

  // C/D layout: col = lane&15, row = (lane>>4)*4 + j  [m89-verified]
  int rbase = r0 + kc * 4;
#pragma unroll
  for (int ct = 0; ct < 8; ++ct) {
    int col = ct * 16 + c16;
#pragma unroll
    for (int j = 0; j < 4; ++j) {
      h[(size_t)(rbase + j) * D + col] = __float2bfloat16(acc[ct][j]);
    }
  }
}

// ---------- Kernel 2: out[n] = (1/deg) * sum_e h[idx[e]] + bias ----------
// One wave per node; lane owns cols 2l,2l+1 (one dword gather per edge).
__global__ __launch_bounds__(256) void agg_h(const __hip_bfloat16* __restrict__ h,
                                             const int* __restrict__ ptr,
                                             const int* __restrict__ idx,
                                             const float* __restrict__ bias,
                                             float* __restrict__ out) {
  int node = blockIdx.x * 4 + (threadIdx.x >> 6);
  int lane = threadIdx.x & 63;
  if (node >= NN) return;
  int p0 = ptr[node], p1 = ptr[node + 1];
  float sx = 0.f, sy = 0.f;
  for (int e = p0; e < p1; ++e) {
    int nid = idx[e];
    __hip_bfloat162 v = ((const __hip_bfloat162*)(h + (size_t)nid * D))[lane];
    sx += __bfloat162float(v.x);
    sy += __bfloat162float(v.y);
  }
  int deg = p1 - p0;
  float inv = (deg > 0) ? (1.0f / (float)deg) : 0.0f;
  float2 b = ((const float2*)bias)[lane];
  float2 r;
  r.x = fmaf(sx, inv, b.x);
  r.y = fmaf(sy, inv, b.y);
  ((float2*)(out + (size_t)node * D))[lane] = r;
}

// ---------- Fallback path (R1): fp32 agg + fp32 rowgemm, no ws needed ----------
__global__ __launch_bounds__(256) void agg_x(const float* __restrict__ x,
                                             const int* __restrict__ ptr,
                                             const int* __restrict__ idx,
                                             float* __restrict__ out) {
  int node = blockIdx.x * 4 + (threadIdx.x >> 6);
  int lane = threadIdx.x & 63;
  if (node >= NN) return;
  int p0 = ptr[node], p1 = ptr[node + 1];
  float sx = 0.f, sy = 0.f;
  for (int e = p0; e < p1; ++e) {
    int nid = idx[e];
    const float2 v = ((const float2*)(x + (size_t)nid * D))[lane];
    sx += v.x;
    sy += v.y;
  }
  int deg = p1 - p0;
  float inv = (deg > 0) ? (1.0f / (float)deg) : 0.0f;
  float2 r;
  r.x = sx * inv;
  r.y = sy * inv;
  ((float2*)(out + (size_t)node * D))[lane] = r;
}

__global__ __launch_bounds__(256) void rowgemm_inplace(float* __restrict__ io,
                                                       const float* __restrict__ W,
                                                       const float* __restrict__ bias) {
  __shared__ float4 Wl[D * 32];
  __shared__ float xr[8][D];
  int tid = threadIdx.x;
  for (int i = tid; i < D * 32; i += 256) Wl[i] = ((const float4*)W)[i];
  int r = tid >> 5;
  int c4 = tid & 31;
  float4 b4 = ((const float4*)bias)[c4];
  __syncthreads();
  const int ngroups = NN / 8;
  for (int g = blockIdx.x; g < ngroups; g += gridDim.x) {
    size_t base = (size_t)g * 8;
    ((float4*)xr)[tid] = ((const float4*)(io + base * D))[tid];
    __syncthreads();
    float4 acc = b4;
#pragma unroll 8
    for (int k = 0; k < D; ++k) {
      float xv = xr[r][k];
      float4 w = Wl[k * 32 + c4];
      acc.x = fmaf(xv, w.x, acc.x);
      acc.y = fmaf(xv, w.y, acc.y);
      acc.z = fmaf(xv, w.z, acc.z);
      acc.w = fmaf(xv, w.w, acc.w);
    }
    ((float4*)(io + (base + (size_t)r) * D))[c4] = acc;
    __syncthreads();
  }
}

extern "C" void kernel_launch(void* const* d_in, const int* in_sizes, int n_in,
                              void* d_out, int out_size, void* d_ws, size_t ws_size,
                              hipStream_t stream) {
  const float* x = (const float*)d_in[0];
  const float* W = (const float*)d_in[1];
  const float* bias = (const float*)d_in[2];
  const int* ptr = (const int*)d_in[3];
  const int* idx = (const int*)d_in[4];
  float* out = (float*)d_out;

  const size_t need = (size_t)NN * D * sizeof(__hip_bfloat16);  // 25.6 MB
  if (ws_size >= need) {
    __hip_bfloat16* h = (__hip_bfloat16*)d_ws;
    gemm_xw_bf16<<<(NN + 63) / 64, 256, 0, stream>>>(x, W, h);
    agg_h<<<NN / 4, 256, 0, stream>>>(h, ptr, idx, bias, out);
  } else {
    agg_x<<<NN / 4, 256, 0, stream>>>(x, ptr, idx, out);
    rowgemm_inplace<<<1280, 256, 0, stream>>>(out, W, bias);
  }
}

// Round 3
// 81.616 us; speedup vs baseline: 2.9128x; 1.9485x over previous
//
#include <hip/hip_runtime.h>
#include <hip/hip_bf16.h>

// GCN conv: out = mean-aggregate(h over CSR) + bias, h = x @ W (bf16 in ws).
// R3: agg_h rebuilt for MLP — 16B/lane gathers (4 edges per dwordx4), full
// unroll for deg==16, shfl-xor cross-group reduction.

#define NN 100000
#define D 128

using short8 = __attribute__((ext_vector_type(8))) short;
using f32x4 = __attribute__((ext_vector_type(4))) float;

__device__ __forceinline__ float bf2f(short s) {
  unsigned int u = ((unsigned int)(unsigned short)s) << 16;
  return __builtin_bit_cast(float, u);
}

// ---------- Kernel 1: h[n][c] = sum_k x[n][k] * W[k][c], h in bf16 ----------
__global__ __launch_bounds__(256) void gemm_xw_bf16(const float* __restrict__ x,
                                                    const float* __restrict__ W,
                                                    __hip_bfloat16* __restrict__ h) {
  __shared__ __hip_bfloat16 Wl[D][D + 8];  // transposed: Wl[col][k]
  int tid = threadIdx.x;
  for (int i = tid; i < D * D; i += 256) {
    int k = i >> 7, c = i & 127;
    Wl[c][k] = __float2bfloat16(W[i]);
  }
  __syncthreads();

  int wid = tid >> 6, lane = tid & 63;
  int r0 = (blockIdx.x * 4 + wid) * 16;
  if (r0 >= NN) return;  // NN % 64 == 0 pattern: 100000 % 16 == 0, waves all-or-nothing
  int c16 = lane & 15;
  int kc = lane >> 4;

  short8 a[4];
  const float* xrow = x + (size_t)(r0 + c16) * D + kc * 8;
#pragma unroll
  for (int kk = 0; kk < 4; ++kk) {
    const float* p = xrow + kk * 32;
#pragma unroll
    for (int j = 0; j < 8; ++j) {
      __hip_bfloat16 bv = __float2bfloat16(p[j]);
      a[kk][j] = *reinterpret_cast<short*>(&bv);
    }
  }

  f32x4 acc[8];
#pragma unroll
  for (int ct = 0; ct < 8; ++ct) acc[ct] = (f32x4)(0.0f);

#pragma unroll
  for (int kk = 0; kk < 4; ++kk) {
#pragma unroll
    for (int ct = 0; ct < 8; ++ct) {
      short8 b = *reinterpret_cast<const short8*>(&Wl[ct * 16 + c16][kk * 32 + kc * 8]);
      acc[ct] = __builtin_amdgcn_mfma_f32_16x16x32_bf16(a[kk], b, acc[ct], 0, 0, 0);
    }
  }

  int rbase = r0 + kc * 4;
#pragma unroll
  for (int ct = 0; ct < 8; ++ct) {
    int col = ct * 16 + c16;
#pragma unroll
    for (int j = 0; j < 4; ++j) {
      h[(size_t)(rbase + j) * D + col] = __float2bfloat16(acc[ct][j]);
    }
  }
}

// ---------- Kernel 2: out[n] = (1/deg) * sum_e h[idx[e]] + bias ----------
// One wave per node. Lane layout: sub = lane&15 (16B chunk within a 256B row),
// grp = lane>>4 (which of 4 edges per gather instruction).
__global__ __launch_bounds__(256) void agg_h16(const __hip_bfloat16* __restrict__ h,
                                               const int* __restrict__ ptr,
                                               const int* __restrict__ idx,
                                               const float* __restrict__ bias,
                                               float* __restrict__ out) {
  int node = blockIdx.x * 4 + (threadIdx.x >> 6);
  int lane = threadIdx.x & 63;
  if (node >= NN) return;
  int p0 = ptr[node], p1 = ptr[node + 1];
  int deg = p1 - p0;
  int sub = lane & 15;
  int grp = lane >> 4;

  float acc[8];
#pragma unroll
  for (int j = 0; j < 8; ++j) acc[j] = 0.0f;

  if (deg == 16) {
    // all 16 idx in one lane-parallel load (lanes replicate via &15 — in bounds)
    int vidx = idx[p0 + sub];
    // issue all 4 gathers before accumulating (4 dwordx4 in flight)
    short8 v[4];
#pragma unroll
    for (int i = 0; i < 4; ++i) {
      int rid = __shfl(vidx, 4 * i + grp);
      v[i] = *reinterpret_cast<const short8*>(h + (size_t)rid * D + sub * 8);
    }
#pragma unroll
    for (int i = 0; i < 4; ++i) {
#pragma unroll
      for (int j = 0; j < 8; ++j) acc[j] += bf2f(v[i][j]);
    }
  } else {
    for (int e = p0; e < p1; e += 4) {
      int ee = e + grp;
      bool valid = (ee < p1);
      int rid = idx[valid ? ee : (p1 - 1)];
      if (valid) {
        short8 v = *reinterpret_cast<const short8*>(h + (size_t)rid * D + sub * 8);
#pragma unroll
        for (int j = 0; j < 8; ++j) acc[j] += bf2f(v[j]);
      }
    }
  }

  // reduce across the 4 groups (xor 16, xor 32)
#pragma unroll
  for (int j = 0; j < 8; ++j) {
    acc[j] += __shfl_xor(acc[j], 16);
    acc[j] += __shfl_xor(acc[j], 32);
  }

  if (grp == 0) {
    float inv = (deg > 0) ? (1.0f / (float)deg) : 0.0f;
    const float4 b0 = ((const float4*)bias)[sub * 2];
    const float4 b1 = ((const float4*)bias)[sub * 2 + 1];
    float4 r0, r1;
    r0.x = fmaf(acc[0], inv, b0.x);
    r0.y = fmaf(acc[1], inv, b0.y);
    r0.z = fmaf(acc[2], inv, b0.z);
    r0.w = fmaf(acc[3], inv, b0.w);
    r1.x = fmaf(acc[4], inv, b1.x);
    r1.y = fmaf(acc[5], inv, b1.y);
    r1.z = fmaf(acc[6], inv, b1.z);
    r1.w = fmaf(acc[7], inv, b1.w);
    float4* orow = (float4*)(out + (size_t)node * D);
    orow[sub * 2] = r0;
    orow[sub * 2 + 1] = r1;
  }
}

// ---------- Fallback path (no ws): fp32 agg + fp32 rowgemm ----------
__global__ __launch_bounds__(256) void agg_x(const float* __restrict__ x,
                                             const int* __restrict__ ptr,
                                             const int* __restrict__ idx,
                                             float* __restrict__ out) {
  int node = blockIdx.x * 4 + (threadIdx.x >> 6);
  int lane = threadIdx.x & 63;
  if (node >= NN) return;
  int p0 = ptr[node], p1 = ptr[node + 1];
  float sx = 0.f, sy = 0.f;
  for (int e = p0; e < p1; ++e) {
    int nid = idx[e];
    const float2 v = ((const float2*)(x + (size_t)nid * D))[lane];
    sx += v.x;
    sy += v.y;
  }
  int deg = p1 - p0;
  float inv = (deg > 0) ? (1.0f / (float)deg) : 0.0f;
  float2 r;
  r.x = sx * inv;
  r.y = sy * inv;
  ((float2*)(out + (size_t)node * D))[lane] = r;
}

__global__ __launch_bounds__(256) void rowgemm_inplace(float* __restrict__ io,
                                                       const float* __restrict__ W,
                                                       const float* __restrict__ bias) {
  __shared__ float4 Wl[D * 32];
  __shared__ float xr[8][D];
  int tid = threadIdx.x;
  for (int i = tid; i < D * 32; i += 256) Wl[i] = ((const float4*)W)[i];
  int r = tid >> 5;
  int c4 = tid & 31;
  float4 b4 = ((const float4*)bias)[c4];
  __syncthreads();
  const int ngroups = NN / 8;
  for (int g = blockIdx.x; g < ngroups; g += gridDim.x) {
    size_t base = (size_t)g * 8;
    ((float4*)xr)[tid] = ((const float4*)(io + base * D))[tid];
    __syncthreads();
    float4 acc = b4;
#pragma unroll 8
    for (int k = 0; k < D; ++k) {
      float xv = xr[r][k];
      float4 w = Wl[k * 32 + c4];
      acc.x = fmaf(xv, w.x, acc.x);
      acc.y = fmaf(xv, w.y, acc.y);
      acc.z = fmaf(xv, w.z, acc.z);
      acc.w = fmaf(xv, w.w, acc.w);
    }
    ((float4*)(io + (base + (size_t)r) * D))[c4] = acc;
    __syncthreads();
  }
}

extern "C" void kernel_launch(void* const* d_in, const int* in_sizes, int n_in,
                              void* d_out, int out_size, void* d_ws, size_t ws_size,
                              hipStream_t stream) {
  const float* x = (const float*)d_in[0];
  const float* W = (const float*)d_in[1];
  const float* bias = (const float*)d_in[2];
  const int* ptr = (const int*)d_in[3];
  const int* idx = (const int*)d_in[4];
  float* out = (float*)d_out;

  const size_t need = (size_t)NN * D * sizeof(__hip_bfloat16);  // 25.6 MB
  if (ws_size >= need) {
    __hip_bfloat16* h = (__hip_bfloat16*)d_ws;
    gemm_xw_bf16<<<(NN + 63) / 64, 256, 0, stream>>>(x, W, h);
    agg_h16<<<NN / 4, 256, 0, stream>>>(h, ptr, idx, bias, out);
  } else {
    agg_x<<<NN / 4, 256, 0, stream>>>(x, ptr, idx, out);
    rowgemm_inplace<<<1280, 256, 0, stream>>>(out, W, bias);
  }
}